// Round 4
// baseline (262.527 us; speedup 1.0000x reference)
//
#include <hip/hip_runtime.h>
#include <math.h>

#define BB 2
#define NN 2048
#define MM 4096
#define DD 256
#define HH 8
#define DK 32
#define KNN 16

typedef __attribute__((ext_vector_type(8))) short short8;
typedef __attribute__((ext_vector_type(4))) float f32x4;
typedef unsigned long long u64;
typedef unsigned short u16;

static __device__ __forceinline__ u16 f2bf(float f) {
    union { float f; unsigned u; } v; v.f = f;
    unsigned r = v.u + 0x7FFF + ((v.u >> 16) & 1);   // round-to-nearest-even
    return (u16)(r >> 16);
}
static __device__ __forceinline__ float bf2f(u16 u) {
    union { unsigned u; float f; } v; v.u = ((unsigned)u) << 16;
    return v.f;
}

// =================== prep: cvt tgt_fea & src_fea to bf16, transpose weights ===================
__global__ __launch_bounds__(256)
void prep_kernel(const float* __restrict__ tgt_fea, const float* __restrict__ src_fea,
                 const float* __restrict__ Wq, const float* __restrict__ Wk,
                 const float* __restrict__ Wv, const float* __restrict__ Wo1,
                 const float* __restrict__ Wo2,
                 u16* __restrict__ tfb, u16* __restrict__ sfb,
                 u16* __restrict__ WTq, u16* __restrict__ WTk, u16* __restrict__ WTv,
                 u16* __restrict__ WTo1, u16* __restrict__ WTo2)
{
    __shared__ float tile[64][65];
    const int bid = blockIdx.x, t = threadIdx.x;
    if (bid < 1536) {                                   // bulk cvt
        const float* in; u16* out; int i;
        if (bid < 1024) { in = tgt_fea; out = tfb; i = bid * 256 + t; }
        else            { in = src_fea; out = sfb; i = (bid - 1024) * 256 + t; }
        float4 a = ((const float4*)in)[i * 2];
        float4 b = ((const float4*)in)[i * 2 + 1];
        short8 s;
        s[0] = (short)f2bf(a.x); s[1] = (short)f2bf(a.y);
        s[2] = (short)f2bf(a.z); s[3] = (short)f2bf(a.w);
        s[4] = (short)f2bf(b.x); s[5] = (short)f2bf(b.y);
        s[6] = (short)f2bf(b.z); s[7] = (short)f2bf(b.w);
        ((short8*)out)[i] = s;
        return;
    }
    const int id = bid - 1536;                          // 0..79: weight transpose
    const int m = id >> 4, tl = id & 15;
    const int tr = (tl >> 2) * 64, tc = (tl & 3) * 64;
    const float* W = m == 0 ? Wq : m == 1 ? Wk : m == 2 ? Wv : m == 3 ? Wo1 : Wo2;
    u16*        O = m == 0 ? WTq : m == 1 ? WTk : m == 2 ? WTv : m == 3 ? WTo1 : WTo2;
    const int c = t & 63, r4 = t >> 6;
    #pragma unroll
    for (int i = 0; i < 16; ++i) {
        const int r = (r4 << 4) + i;
        tile[r][c] = W[(size_t)(tr + r) * 256 + tc + c];
    }
    __syncthreads();
    #pragma unroll
    for (int i = 0; i < 16; ++i) {
        const int cc = (r4 << 4) + i;
        O[(size_t)(tc + cc) * 256 + tr + c] = f2bf(tile[c][cc]);
    }
}

// =================== mega: knn + KV-GEMM(128x128) + Q-GEMM(64x64) + zero(avg) ===================
// block ranges: [0,1024) knn | [1024,1280) KV | [1280,1536) Q | [1536,2048) zero
__global__ __launch_bounds__(256)
void mega_kernel(const float* __restrict__ src, const float* __restrict__ tgt,
                 int* __restrict__ knn_idx,
                 const u16* __restrict__ tfb, const u16* __restrict__ sfb,
                 const u16* __restrict__ WTq, const u16* __restrict__ WTkv,
                 const float* __restrict__ bq, const float* __restrict__ bk,
                 const float* __restrict__ bv,
                 float* __restrict__ Qb, u16* __restrict__ Kbf, u16* __restrict__ Vbf,
                 float* __restrict__ avg)
{
    __shared__ u16 As[128 * 64];
    __shared__ u16 Bs[128 * 64];
    const int bid = blockIdx.x;
    const int t = threadIdx.x;
    const int lane = t & 63;

    if (bid < 1024) {
        // ---- kNN: wave-per-query, packed-u64 exact (f64, np tie-break by index)
        const int bn = (bid << 2) + (t >> 6);
        const int b = bn >> 11;
        const float* sp = src + (size_t)bn * 3;
        const double px = sp[0], py = sp[1], pz = sp[2];
        const double x2 = px * px + py * py + pz * pz;
        const float* tb = tgt + (size_t)b * MM * 3;
        u64 pk[64];
        #pragma unroll
        for (int j = 0; j < 64; ++j) {
            const int m = (j << 6) + lane;
            const double tx = tb[m * 3 + 0], ty = tb[m * 3 + 1], tz = tb[m * 3 + 2];
            const double y2 = tx * tx + ty * ty + tz * tz;
            const double dt = px * tx + py * ty + pz * tz;
            double d = (x2 + y2) - 2.0 * dt;
            d = d > 0.0 ? d : 0.0;
            pk[j] = (((u64)__double_as_longlong(d)) & ~0xFFFULL) | (u64)m;
        }
        u64 last1 = 0;
        unsigned myidx = 0;
        for (int sel = 0; sel < 16; ++sel) {
            u64 b0 = ~0ULL, b1 = ~0ULL, b2 = ~0ULL, b3 = ~0ULL;
            #pragma unroll
            for (int j = 0; j < 64; j += 4) {
                u64 u0 = pk[j + 0] - last1; b0 = u0 < b0 ? u0 : b0;
                u64 u1 = pk[j + 1] - last1; b1 = u1 < b1 ? u1 : b1;
                u64 u2 = pk[j + 2] - last1; b2 = u2 < b2 ? u2 : b2;
                u64 u3 = pk[j + 3] - last1; b3 = u3 < b3 ? u3 : b3;
            }
            u64 best = b0 < b1 ? b0 : b1;
            u64 bst2 = b2 < b3 ? b2 : b3;
            best = best < bst2 ? best : bst2;
            #pragma unroll
            for (int s = 32; s; s >>= 1) {
                u64 o = __shfl_xor(best, s, 64);
                best = o < best ? o : best;
            }
            const u64 winner = best + last1;
            if (lane == sel) myidx = (unsigned)(winner & 0xFFF);
            last1 = winner + 1;
        }
        if (lane < 16) knn_idx[(size_t)bn * KNN + lane] = (int)myidx;
        return;
    }

    if (bid < 1280) {
        // ---- KV GEMM: C[8192][512] = tfb @ [WTk|WTv]^T, 128x128 tile, bf16 out
        const int kb_id = bid - 1024;
        const int rt = kb_id & 63, ct = kb_id >> 6;
        const size_t row0 = (size_t)rt * 128;
        const int col0 = ct * 128;
        const int w = t >> 6;
        const int wr2 = (w >> 1) * 64, wc2 = (w & 1) * 64;
        f32x4 acc[4][4] = {};
        for (int k0 = 0; k0 < 256; k0 += 64) {
            #pragma unroll
            for (int e = 0; e < 4; ++e) {
                const int u = t + (e << 8);
                const int r = u >> 3, kc = (u & 7) << 3;
                const int off = ((r << 7) + (kc << 1)) ^ ((r & 7) << 4);
                *(short8*)((char*)As + off) = *(const short8*)(tfb + (row0 + r) * 256 + k0 + kc);
                *(short8*)((char*)Bs + off) = *(const short8*)(WTkv + (size_t)(col0 + r) * 256 + k0 + kc);
            }
            __syncthreads();
            #pragma unroll
            for (int kk = 0; kk < 64; kk += 32) {
                const int kbo = (kk + ((lane >> 4) << 3)) << 1;
                short8 af[4], bfr[4];
                #pragma unroll
                for (int i = 0; i < 4; ++i) {
                    const int ra = wr2 + (i << 4) + (lane & 15);
                    af[i]  = *(const short8*)((const char*)As + (((ra << 7) + kbo) ^ ((ra & 7) << 4)));
                    const int rb = wc2 + (i << 4) + (lane & 15);
                    bfr[i] = *(const short8*)((const char*)Bs + (((rb << 7) + kbo) ^ ((rb & 7) << 4)));
                }
                #pragma unroll
                for (int mi = 0; mi < 4; ++mi)
                    #pragma unroll
                    for (int ni = 0; ni < 4; ++ni)
                        acc[mi][ni] = __builtin_amdgcn_mfma_f32_16x16x32_bf16(af[mi], bfr[ni], acc[mi][ni], 0, 0, 0);
            }
            __syncthreads();
        }
        const bool isv = col0 >= 256;
        u16* ob = isv ? Vbf : Kbf;
        const float* bs = isv ? bv : bk;
        const int cb = (isv ? col0 - 256 : col0) + wc2;
        const int cq = lane & 15, rq = (lane >> 4) << 2;
        #pragma unroll
        for (int ni = 0; ni < 4; ++ni) {
            const int c = cb + (ni << 4) + cq;
            const float bval = bs[c];
            #pragma unroll
            for (int mi = 0; mi < 4; ++mi) {
                const size_t r = row0 + wr2 + (mi << 4) + rq;
                #pragma unroll
                for (int e = 0; e < 4; ++e)
                    ob[(r + e) * 256 + c] = f2bf(acc[mi][ni][e] + bval);
            }
        }
        return;
    }

    if (bid < 1536) {
        // ---- Q GEMM: Qb[4096][256] f32 = sfb @ WTq^T, 64x64 tile
        const int qb_id = bid - 1280;
        const int rt = qb_id & 63, ct = qb_id >> 6;
        const size_t row0 = (size_t)rt * 64;
        const int col0 = ct * 64;
        const int w = t >> 6;
        const int wr = (w >> 1) * 32, wc = (w & 1) * 32;
        f32x4 acc[2][2] = {};
        for (int k0 = 0; k0 < 256; k0 += 64) {
            #pragma unroll
            for (int e = 0; e < 2; ++e) {
                const int u = t + (e << 8);
                const int r = u >> 3, kc = (u & 7) << 3;
                const int off = ((r << 7) + (kc << 1)) ^ ((r & 7) << 4);
                *(short8*)((char*)As + off) = *(const short8*)(sfb + (row0 + r) * 256 + k0 + kc);
                *(short8*)((char*)Bs + off) = *(const short8*)(WTq + (size_t)(col0 + r) * 256 + k0 + kc);
            }
            __syncthreads();
            #pragma unroll
            for (int kk = 0; kk < 64; kk += 32) {
                const int kbo = (kk + ((lane >> 4) << 3)) << 1;
                short8 af[2], bfr[2];
                #pragma unroll
                for (int i = 0; i < 2; ++i) {
                    const int ra = wr + (i << 4) + (lane & 15);
                    af[i]  = *(const short8*)((const char*)As + (((ra << 7) + kbo) ^ ((ra & 7) << 4)));
                    const int rb = wc + (i << 4) + (lane & 15);
                    bfr[i] = *(const short8*)((const char*)Bs + (((rb << 7) + kbo) ^ ((rb & 7) << 4)));
                }
                #pragma unroll
                for (int mi = 0; mi < 2; ++mi)
                    #pragma unroll
                    for (int ni = 0; ni < 2; ++ni)
                        acc[mi][ni] = __builtin_amdgcn_mfma_f32_16x16x32_bf16(af[mi], bfr[ni], acc[mi][ni], 0, 0, 0);
            }
            __syncthreads();
        }
        const int cq = lane & 15, rq = (lane >> 4) << 2;
        #pragma unroll
        for (int ni = 0; ni < 2; ++ni) {
            const int c = col0 + wc + (ni << 4) + cq;
            const float bval = bq[c];
            #pragma unroll
            for (int mi = 0; mi < 2; ++mi) {
                const size_t rbase = (row0 + wr + (mi << 4) + rq) * 256 + c;
                #pragma unroll
                for (int e = 0; e < 4; ++e)
                    Qb[rbase + (size_t)e * 256] = acc[mi][ni][e] + bval;
            }
        }
        return;
    }

    // ---- zero avg_attn: 16.7M f32 = 4.19M f32x4 over 512 blocks
    {
        const int zb = bid - 1536;
        f32x4 z = {0.f, 0.f, 0.f, 0.f};
        f32x4* pz = (f32x4*)avg;
        const int base = zb * 256 + t;
        #pragma unroll
        for (int i = 0; i < 32; ++i)
            pz[base + i * 131072] = z;
    }
}

// =================== attn: gathered 16-way attention + residual; scatter avg ===================
__global__ __launch_bounds__(256)
void attn_kernel(const float* __restrict__ Q, const u16* __restrict__ Kb,
                 const u16* __restrict__ Vb, const int* __restrict__ knn_idx,
                 const float* __restrict__ src_fea,
                 u16* __restrict__ Xb, float* __restrict__ avg_attn)
{
    __shared__ float Kt[KNN][257];
    __shared__ float Vt[KNN][257];
    __shared__ float q[DD];
    __shared__ float sc[HH][KNN];
    __shared__ float pw[HH][KNN];
    __shared__ int   idx[KNN];
    const int bn = blockIdx.x;
    const int b  = bn >> 11;
    const int t  = threadIdx.x;
    if (t < KNN) idx[t] = knn_idx[(size_t)bn * KNN + t];
    q[t] = Q[(size_t)bn * DD + t];
    __syncthreads();
    #pragma unroll
    for (int r = 0; r < KNN; ++r) {
        size_t rowoff = ((size_t)b * MM + idx[r]) * DD;
        Kt[r][t] = bf2f(Kb[rowoff + t]);
        Vt[r][t] = bf2f(Vb[rowoff + t]);
    }
    __syncthreads();
    if (t < HH * KNN) {
        int h = t >> 4, k = t & 15;
        float s = 0.f;
        const float* qh = &q[h * DK];
        const float* kh = &Kt[k][h * DK];
        #pragma unroll
        for (int j = 0; j < DK; ++j) s = fmaf(qh[j], kh[j], s);
        sc[h][k] = s * 0.17677669529663688f;
    }
    __syncthreads();
    if (t < HH) {
        float mx = -1e30f;
        #pragma unroll
        for (int k = 0; k < KNN; ++k) mx = fmaxf(mx, sc[t][k]);
        float e[KNN]; float sum = 0.f;
        #pragma unroll
        for (int k = 0; k < KNN; ++k) { e[k] = expf(sc[t][k] - mx); sum += e[k]; }
        float inv = 1.0f / sum;
        #pragma unroll
        for (int k = 0; k < KNN; ++k) pw[t][k] = e[k] * inv;
    }
    __syncthreads();
    if (t < KNN) {
        float a = 0.f;
        #pragma unroll
        for (int h = 0; h < HH; ++h) a += pw[h][t];
        avg_attn[(size_t)bn * MM + idx[t]] = a * (1.0f / HH);
    }
    {
        int h = t >> 5;
        float acc = 0.f;
        #pragma unroll
        for (int k = 0; k < KNN; ++k) acc = fmaf(pw[h][k], Vt[k][t], acc);
        Xb[(size_t)bn * DD + t] = f2bf(acc + src_fea[(size_t)bn * DD + t]);
    }
}

// =================== row-GEMM (64 rows x 256 cols), LN=1: +LayerNorm+ReLU -> bf16 ===================
template<int LN>
__global__ __launch_bounds__(256)
void gemm_row256(const u16* __restrict__ A, const u16* __restrict__ WT,
                 const float* __restrict__ bias,
                 const float* __restrict__ g, const float* __restrict__ bvec,
                 u16* __restrict__ outb, float* __restrict__ outf)
{
    __shared__ u16 As[64 * 64];        // 8KB
    __shared__ u16 Bs[256 * 64];       // 32KB
    const int t = threadIdx.x, lane = t & 63, w = t >> 6;
    const size_t row0 = (size_t)blockIdx.x * 64;
    f32x4 acc[4][4] = {};
    for (int k0 = 0; k0 < 256; k0 += 64) {
        #pragma unroll
        for (int e = 0; e < 2; ++e) {
            const int u = t + (e << 8);
            const int r = u >> 3, kc = (u & 7) << 3;
            const int off = ((r << 7) + (kc << 1)) ^ ((r & 7) << 4);
            *(short8*)((char*)As + off) = *(const short8*)(A + (row0 + r) * 256 + k0 + kc);
        }
        #pragma unroll
        for (int e = 0; e < 8; ++e) {
            const int u = t + (e << 8);
            const int r = u >> 3, kc = (u & 7) << 3;
            const int off = ((r << 7) + (kc << 1)) ^ ((r & 7) << 4);
            *(short8*)((char*)Bs + off) = *(const short8*)(WT + (size_t)r * 256 + k0 + kc);
        }
        __syncthreads();
        #pragma unroll
        for (int kk = 0; kk < 64; kk += 32) {
            const int kbo = (kk + ((lane >> 4) << 3)) << 1;
            short8 af[4], bfr[4];
            #pragma unroll
            for (int i = 0; i < 4; ++i) {
                const int ra = (i << 4) + (lane & 15);
                af[i]  = *(const short8*)((const char*)As + (((ra << 7) + kbo) ^ ((ra & 7) << 4)));
                const int rb = (w << 6) + (i << 4) + (lane & 15);
                bfr[i] = *(const short8*)((const char*)Bs + (((rb << 7) + kbo) ^ ((rb & 7) << 4)));
            }
            #pragma unroll
            for (int mi = 0; mi < 4; ++mi)
                #pragma unroll
                for (int ni = 0; ni < 4; ++ni)
                    acc[mi][ni] = __builtin_amdgcn_mfma_f32_16x16x32_bf16(af[mi], bfr[ni], acc[mi][ni], 0, 0, 0);
        }
        __syncthreads();
    }
    const int cq = lane & 15, rq = (lane >> 4) << 2;
    #pragma unroll
    for (int ni = 0; ni < 4; ++ni) {
        const float bval = bias[(w << 6) + (ni << 4) + cq];
        #pragma unroll
        for (int mi = 0; mi < 4; ++mi)
            #pragma unroll
            for (int e = 0; e < 4; ++e)
                acc[mi][ni][e] += bval;
    }
    if (LN) {
        float* ws1 = (float*)As;            // [4 waves][64 rows]
        float* ws2 = ws1 + 256;
        float s1v[4][4], s2v[4][4];
        #pragma unroll
        for (int mi = 0; mi < 4; ++mi)
            #pragma unroll
            for (int e = 0; e < 4; ++e) {
                float s1 = 0.f, s2 = 0.f;
                #pragma unroll
                for (int ni = 0; ni < 4; ++ni) { const float y = acc[mi][ni][e]; s1 += y; s2 += y * y; }
                #pragma unroll
                for (int s = 8; s; s >>= 1) { s1 += __shfl_xor(s1, s, 64); s2 += __shfl_xor(s2, s, 64); }
                s1v[mi][e] = s1; s2v[mi][e] = s2;
            }
        if (cq == 0) {
            #pragma unroll
            for (int mi = 0; mi < 4; ++mi)
                #pragma unroll
                for (int e = 0; e < 4; ++e) {
                    const int r = (mi << 4) + rq + e;
                    ws1[(w << 6) + r] = s1v[mi][e];
                    ws2[(w << 6) + r] = s2v[mi][e];
                }
        }
        __syncthreads();
        float g4[4], b4[4];
        #pragma unroll
        for (int ni = 0; ni < 4; ++ni) {
            const int c = (w << 6) + (ni << 4) + cq;
            g4[ni] = g[c]; b4[ni] = bvec[c];
        }
        #pragma unroll
        for (int mi = 0; mi < 4; ++mi)
            #pragma unroll
            for (int e = 0; e < 4; ++e) {
                const int r = (mi << 4) + rq + e;
                const float s1 = ws1[r] + ws1[64 + r] + ws1[128 + r] + ws1[192 + r];
                const float s2 = ws2[r] + ws2[64 + r] + ws2[128 + r] + ws2[192 + r];
                const float mean = s1 * (1.0f / 256.0f);
                const float var = s2 * (1.0f / 256.0f) - mean * mean;
                const float rstd = 1.0f / sqrtf(var + 1e-5f);
                #pragma unroll
                for (int ni = 0; ni < 4; ++ni) {
                    const int c = (w << 6) + (ni << 4) + cq;
                    float y = (acc[mi][ni][e] - mean) * rstd * g4[ni] + b4[ni];
                    outb[(row0 + r) * 256 + c] = f2bf(fmaxf(y, 0.0f));
                }
            }
    } else {
        #pragma unroll
        for (int ni = 0; ni < 4; ++ni) {
            const int c = (w << 6) + (ni << 4) + cq;
            #pragma unroll
            for (int mi = 0; mi < 4; ++mi) {
                const size_t rbase = (row0 + (mi << 4) + rq) * 256 + c;
                #pragma unroll
                for (int e = 0; e < 4; ++e)
                    outf[rbase + (size_t)e * 256] = acc[mi][ni][e];
            }
        }
    }
}

extern "C" void kernel_launch(void* const* d_in, const int* in_sizes, int n_in,
                              void* d_out, int out_size, void* d_ws, size_t ws_size,
                              hipStream_t stream) {
    const float* src     = (const float*)d_in[0];
    const float* tgt     = (const float*)d_in[1];
    const float* src_fea = (const float*)d_in[2];
    const float* tgt_fea = (const float*)d_in[3];
    const float* Wq  = (const float*)d_in[4];   const float* bq  = (const float*)d_in[5];
    const float* Wk  = (const float*)d_in[6];   const float* bk  = (const float*)d_in[7];
    const float* Wv  = (const float*)d_in[8];   const float* bv  = (const float*)d_in[9];
    const float* Wo1 = (const float*)d_in[10];  const float* bo1 = (const float*)d_in[11];
    const float* lng = (const float*)d_in[12];  const float* lnb = (const float*)d_in[13];
    const float* Wo2 = (const float*)d_in[14];  const float* bo2 = (const float*)d_in[15];
    (void)in_sizes; (void)n_in; (void)out_size; (void)ws_size;

    float* out     = (float*)d_out;
    float* updated = out;                                   // [B,N,D] f32
    float* avg     = out + (size_t)BB * NN * DD;            // [B,N,M] f32

    char* p = (char*)d_ws;
    u16* tfb  = (u16*)p;   p += (size_t)BB * MM * DD * 2;   // 4MB
    u16* sfb  = (u16*)p;   p += (size_t)BB * NN * DD * 2;   // 2MB
    u16* WTq  = (u16*)p;   p += 256 * 256 * 2;
    u16* WTk  = (u16*)p;   p += 256 * 256 * 2;              // WTk|WTv contiguous = WTkv
    u16* WTv  = (u16*)p;   p += 256 * 256 * 2;
    u16* WTo1 = (u16*)p;   p += 256 * 256 * 2;
    u16* WTo2 = (u16*)p;   p += 256 * 256 * 2;
    float* Qb = (float*)p; p += (size_t)BB * NN * DD * 4;   // 4MB
    u16* Kbf  = (u16*)p;   p += (size_t)BB * MM * DD * 2;   // 4MB
    u16* Vbf  = (u16*)p;   p += (size_t)BB * MM * DD * 2;   // 4MB
    int* knn  = (int*)p;   p += (size_t)BB * NN * KNN * 4;  // 256KB
    u16* Xbf  = (u16*)p;   p += (size_t)BB * NN * DD * 2;   // 2MB
    u16* Hbf  = (u16*)p;   p += (size_t)BB * NN * DD * 2;   // 2MB

    dim3 blk(256);
    prep_kernel<<<1616, blk, 0, stream>>>(tgt_fea, src_fea, Wq, Wk, Wv, Wo1, Wo2,
                                          tfb, sfb, WTq, WTk, WTv, WTo1, WTo2);
    mega_kernel<<<2048, blk, 0, stream>>>(src, tgt, knn, tfb, sfb, WTq, WTk,
                                          bq, bk, bv, Qb, Kbf, Vbf, avg);
    attn_kernel<<<BB * NN, blk, 0, stream>>>(Qb, Kbf, Vbf, knn, src_fea, Xbf, avg);
    gemm_row256<1><<<BB * NN / 64, blk, 0, stream>>>(Xbf, WTo1, bo1, lng, lnb, Hbf, nullptr);
    gemm_row256<0><<<BB * NN / 64, blk, 0, stream>>>(Hbf, WTo2, bo2, nullptr, nullptr, nullptr, updated);
}

// Round 5
// 201.485 us; speedup vs baseline: 1.3030x; 1.3030x over previous
//
#include <hip/hip_runtime.h>
#include <math.h>

#define BB 2
#define NN 2048
#define MM 4096
#define DD 256
#define HH 8
#define DK 32
#define KNN 16

typedef __attribute__((ext_vector_type(8))) short short8;
typedef __attribute__((ext_vector_type(4))) float f32x4;
typedef unsigned long long u64;
typedef unsigned short u16;

static __device__ __forceinline__ u16 f2bf(float f) {
    union { float f; unsigned u; } v; v.f = f;
    unsigned r = v.u + 0x7FFF + ((v.u >> 16) & 1);   // round-to-nearest-even
    return (u16)(r >> 16);
}
static __device__ __forceinline__ float bf2f(u16 u) {
    union { unsigned u; float f; } v; v.u = ((unsigned)u) << 16;
    return v.f;
}

// =================== wtrans: transpose + cvt the five 256x256 weights ===================
__global__ __launch_bounds__(256)
void wtrans(const float* W0, const float* W1, const float* W2, const float* W3, const float* W4,
            u16* O0, u16* O1, u16* O2, u16* O3, u16* O4)
{
    __shared__ float tile[64][65];
    const int bid = blockIdx.x;               // 5 * 16 blocks
    const int m = bid >> 4, tl = bid & 15;
    const int tr = (tl >> 2) * 64, tc = (tl & 3) * 64;
    const float* W = m == 0 ? W0 : m == 1 ? W1 : m == 2 ? W2 : m == 3 ? W3 : W4;
    u16*        O = m == 0 ? O0 : m == 1 ? O1 : m == 2 ? O2 : m == 3 ? O3 : O4;
    const int c = threadIdx.x & 63, r4 = threadIdx.x >> 6;
    #pragma unroll
    for (int i = 0; i < 16; ++i) {
        const int r = (r4 << 4) + i;
        tile[r][c] = W[(size_t)(tr + r) * 256 + tc + c];
    }
    __syncthreads();
    #pragma unroll
    for (int i = 0; i < 16; ++i) {
        const int cc = (r4 << 4) + i;
        O[(size_t)(tc + cc) * 256 + tr + c] = f2bf(tile[c][cc]);
    }
}

// 64x64-tile bf16 MFMA GEMM body; A staged from f32 with inline cvt.
static __device__ __forceinline__ void gemm64_body(
    const float* __restrict__ A, size_t row0, const u16* __restrict__ WT, int col0,
    u16* As, u16* Bs, int t, f32x4 acc[2][2])
{
    const int lane = t & 63, w = t >> 6;
    const int wr = (w >> 1) * 32, wc = (w & 1) * 32;
    for (int k0 = 0; k0 < 256; k0 += 64) {
        #pragma unroll
        for (int e = 0; e < 2; ++e) {
            const int flat = t + (e << 8);
            const int r = flat >> 3, kc = (flat & 7) << 3;
            const int off = ((r << 7) + (kc << 1)) ^ ((r & 7) << 4);
            const float* ap = A + (row0 + r) * 256 + k0 + kc;
            float4 a0 = *(const float4*)ap;
            float4 a1 = *(const float4*)(ap + 4);
            short8 s;
            s[0] = (short)f2bf(a0.x); s[1] = (short)f2bf(a0.y);
            s[2] = (short)f2bf(a0.z); s[3] = (short)f2bf(a0.w);
            s[4] = (short)f2bf(a1.x); s[5] = (short)f2bf(a1.y);
            s[6] = (short)f2bf(a1.z); s[7] = (short)f2bf(a1.w);
            *(short8*)((char*)As + off) = s;
            *(short8*)((char*)Bs + off) = *(const short8*)(WT + (size_t)(col0 + r) * 256 + k0 + kc);
        }
        __syncthreads();
        #pragma unroll
        for (int kk = 0; kk < 64; kk += 32) {
            const int kbo = (kk + ((lane >> 4) << 3)) << 1;
            short8 af[2], bfr[2];
            #pragma unroll
            for (int i = 0; i < 2; ++i) {
                const int ra = wr + (i << 4) + (lane & 15);
                af[i]  = *(const short8*)((const char*)As + (((ra << 7) + kbo) ^ ((ra & 7) << 4)));
                const int rb = wc + (i << 4) + (lane & 15);
                bfr[i] = *(const short8*)((const char*)Bs + (((rb << 7) + kbo) ^ ((rb & 7) << 4)));
            }
            #pragma unroll
            for (int mi = 0; mi < 2; ++mi)
                #pragma unroll
                for (int ni = 0; ni < 2; ++ni)
                    acc[mi][ni] = __builtin_amdgcn_mfma_f32_16x16x32_bf16(af[mi], bfr[ni], acc[mi][ni], 0, 0, 0);
        }
        __syncthreads();
    }
}

// =================== mega: knn + KV-GEMM + Q-GEMM + zero(avg), role-interleaved ===================
// 2816 blocks = 256 groups x 11 roles: 0-3 knn | 4-7 KV | 8 Q | 9-10 zero
__global__ __launch_bounds__(256, 4)
void mega_kernel(const float* __restrict__ src, const float* __restrict__ tgt,
                 int* __restrict__ knn_idx,
                 const float* __restrict__ tgt_fea, const float* __restrict__ src_fea,
                 const u16* __restrict__ WTq, const u16* __restrict__ WTkv,
                 const float* __restrict__ bq, const float* __restrict__ bk,
                 const float* __restrict__ bv,
                 float* __restrict__ Qb, u16* __restrict__ Kbf, u16* __restrict__ Vbf,
                 float* __restrict__ avg)
{
    __shared__ u16 As[64 * 64];   // 8KB
    __shared__ u16 Bs[64 * 64];   // 8KB
    const int bid = blockIdx.x;
    const int t = threadIdx.x;
    const int lane = t & 63;
    const int lid = bid / 11;
    const int role = bid % 11;

    if (role < 4) {
        // ---- kNN: wave-per-query; u32 fixed-point keys, top-20 superset, exact f64 re-rank.
        const int kb = lid * 4 + role;                 // 0..1023
        const int bn = (kb << 2) + (t >> 6);           // 0..4095
        const int b = bn >> 11;
        const float* sp = src + (size_t)bn * 3;
        const float px = sp[0], py = sp[1], pz = sp[2];
        const float x2 = px * px + py * py + pz * pz;
        const float* tb = tgt + (size_t)b * MM * 3;
        unsigned key[64];
        #pragma unroll
        for (int j = 0; j < 64; ++j) {
            const int m = (j << 6) + lane;
            const float tx = tb[m * 3 + 0], ty = tb[m * 3 + 1], tz = tb[m * 3 + 2];
            const float y2 = tx * tx + ty * ty + tz * tz;
            const float dt = px * tx + py * ty + pz * tz;
            float d = (x2 + y2) - 2.0f * dt;
            d = d > 0.f ? d : 0.f;
            const unsigned q20 = (unsigned)fminf(d * 32768.0f, 1048575.0f);
            key[j] = (q20 << 12) | (unsigned)m;
        }
        unsigned last1 = 0;
        unsigned mykey = 0xFFFFFFFFu;
        for (int sel = 0; sel < 20; ++sel) {
            unsigned c0 = ~0u, c1 = ~0u, c2 = ~0u, c3 = ~0u;
            #pragma unroll
            for (int j = 0; j < 64; j += 4) {
                const unsigned u0 = key[j + 0] - last1; c0 = u0 < c0 ? u0 : c0;
                const unsigned u1 = key[j + 1] - last1; c1 = u1 < c1 ? u1 : c1;
                const unsigned u2 = key[j + 2] - last1; c2 = u2 < c2 ? u2 : c2;
                const unsigned u3 = key[j + 3] - last1; c3 = u3 < c3 ? u3 : c3;
            }
            unsigned best = c0 < c1 ? c0 : c1;
            const unsigned bst2 = c2 < c3 ? c2 : c3;
            best = best < bst2 ? best : bst2;
            #pragma unroll
            for (int s = 32; s; s >>= 1) {
                const unsigned o = __shfl_xor(best, s, 64);
                best = o < best ? o : best;
            }
            const unsigned winner = best + last1;
            if (lane == sel) mykey = winner;
            last1 = winner + 1;
        }
        const int midx = (int)(mykey & 0xFFFu);
        u64 ex = ~0ULL;
        if (lane < 20) {                               // exact f64 distance, np-order key
            const float* tp = tb + (size_t)midx * 3;
            const double pxd = px, pyd = py, pzd = pz;
            const double tx = tp[0], ty = tp[1], tz = tp[2];
            const double x2d = pxd * pxd + pyd * pyd + pzd * pzd;
            const double y2d = tx * tx + ty * ty + tz * tz;
            const double dtd = pxd * tx + pyd * ty + pzd * tz;
            double dd = (x2d + y2d) - 2.0 * dtd;
            dd = dd > 0.0 ? dd : 0.0;
            ex = (((u64)__double_as_longlong(dd)) & ~0xFFFULL) | (u64)midx;
        }
        int rank = 0;
        #pragma unroll
        for (int i = 0; i < 20; ++i) {
            const u64 o = __shfl(ex, i, 64);
            rank += (o < ex) ? 1 : 0;
        }
        if (lane < 20 && rank < 16)
            knn_idx[(size_t)bn * KNN + rank] = midx;
        return;
    }

    if (role < 8) {
        // ---- KV GEMM: [8192][512] = tgt_fea @ [WTk|WTv]^T, bf16 out, 64x64 tile
        const int kvb = lid * 4 + (role - 4);          // 0..1023
        const size_t row0 = (size_t)(kvb >> 3) * 64;
        const int col0 = (kvb & 7) * 64;
        f32x4 acc[2][2] = {};
        gemm64_body(tgt_fea, row0, WTkv, col0, As, Bs, t, acc);
        const int w = t >> 6;
        const int wr = (w >> 1) * 32, wc = (w & 1) * 32;
        const bool isv = col0 >= 256;
        u16* ob = isv ? Vbf : Kbf;
        const float* bs = isv ? bv : bk;
        const int cb = (isv ? col0 - 256 : col0) + wc;
        const int cq = lane & 15, rq = (lane >> 4) << 2;
        #pragma unroll
        for (int ni = 0; ni < 2; ++ni) {
            const int c = cb + (ni << 4) + cq;
            const float bval = bs[c];
            #pragma unroll
            for (int mi = 0; mi < 2; ++mi) {
                const size_t r = row0 + wr + (mi << 4) + rq;
                #pragma unroll
                for (int e = 0; e < 4; ++e)
                    ob[(r + e) * 256 + c] = f2bf(acc[mi][ni][e] + bval);
            }
        }
        return;
    }

    if (role == 8) {
        // ---- Q GEMM: [4096][256] f32 = src_fea @ WTq^T, 64x64 tile
        const int qb = lid;                            // 0..255
        const size_t row0 = (size_t)(qb >> 2) * 64;
        const int col0 = (qb & 3) * 64;
        f32x4 acc[2][2] = {};
        gemm64_body(src_fea, row0, WTq, col0, As, Bs, t, acc);
        const int w = t >> 6;
        const int wr = (w >> 1) * 32, wc = (w & 1) * 32;
        const int cq = lane & 15, rq = (lane >> 4) << 2;
        #pragma unroll
        for (int ni = 0; ni < 2; ++ni) {
            const int c = col0 + wc + (ni << 4) + cq;
            const float bval = bq[c];
            #pragma unroll
            for (int mi = 0; mi < 2; ++mi) {
                const size_t rbase = (row0 + wr + (mi << 4) + rq) * 256 + c;
                #pragma unroll
                for (int e = 0; e < 4; ++e)
                    Qb[rbase + (size_t)e * 256] = acc[mi][ni][e] + bval;
            }
        }
        return;
    }

    // ---- zero avg_attn: 16.78M f32 via f32x4
    {
        const int zb = lid * 2 + (role - 9);           // 0..511
        f32x4 z = {0.f, 0.f, 0.f, 0.f};
        f32x4* pz = (f32x4*)avg;
        const int base = zb * 256 + t;
        #pragma unroll
        for (int i = 0; i < 32; ++i)
            pz[base + i * 131072] = z;
    }
}

// =================== attn: gathered 16-way attention + residual; scatter avg ===================
__global__ __launch_bounds__(256)
void attn_kernel(const float* __restrict__ Q, const u16* __restrict__ Kb,
                 const u16* __restrict__ Vb, const int* __restrict__ knn_idx,
                 const float* __restrict__ src_fea,
                 u16* __restrict__ Xb, float* __restrict__ avg_attn)
{
    __shared__ float Kt[KNN][257];
    __shared__ float Vt[KNN][257];
    __shared__ float q[DD];
    __shared__ float sc[HH][KNN];
    __shared__ float pw[HH][KNN];
    __shared__ int   idx[KNN];
    const int bn = blockIdx.x;
    const int b  = bn >> 11;
    const int t  = threadIdx.x;
    if (t < KNN) idx[t] = knn_idx[(size_t)bn * KNN + t];
    q[t] = Q[(size_t)bn * DD + t];
    __syncthreads();
    {   // vectorized gather: 8 rows x 32 lanes x short8, two rounds
        const int l32 = t & 31, rg = t >> 5;
        #pragma unroll
        for (int rr = 0; rr < 2; ++rr) {
            const int r = (rr << 3) + rg;
            const size_t rowoff = ((size_t)b * MM + idx[r]) * DD + (l32 << 3);
            const short8 kv = *(const short8*)(Kb + rowoff);
            const short8 vv = *(const short8*)(Vb + rowoff);
            #pragma unroll
            for (int e = 0; e < 8; ++e) {
                Kt[r][(l32 << 3) + e] = bf2f((u16)kv[e]);
                Vt[r][(l32 << 3) + e] = bf2f((u16)vv[e]);
            }
        }
    }
    __syncthreads();
    if (t < HH * KNN) {
        int h = t >> 4, k = t & 15;
        float s = 0.f;
        const float* qh = &q[h * DK];
        const float* kh = &Kt[k][h * DK];
        #pragma unroll
        for (int j = 0; j < DK; ++j) s = fmaf(qh[j], kh[j], s);
        sc[h][k] = s * 0.17677669529663688f;
    }
    __syncthreads();
    if (t < HH) {
        float mx = -1e30f;
        #pragma unroll
        for (int k = 0; k < KNN; ++k) mx = fmaxf(mx, sc[t][k]);
        float e[KNN]; float sum = 0.f;
        #pragma unroll
        for (int k = 0; k < KNN; ++k) { e[k] = expf(sc[t][k] - mx); sum += e[k]; }
        float inv = 1.0f / sum;
        #pragma unroll
        for (int k = 0; k < KNN; ++k) pw[t][k] = e[k] * inv;
    }
    __syncthreads();
    if (t < KNN) {
        float a = 0.f;
        #pragma unroll
        for (int h = 0; h < HH; ++h) a += pw[h][t];
        avg_attn[(size_t)bn * MM + idx[t]] = a * (1.0f / HH);
    }
    {
        int h = t >> 5;
        float acc = 0.f;
        #pragma unroll
        for (int k = 0; k < KNN; ++k) acc = fmaf(pw[h][k], Vt[k][t], acc);
        Xb[(size_t)bn * DD + t] = f2bf(acc + src_fea[(size_t)bn * DD + t]);
    }
}

// =================== row-GEMM (64 rows x 256 cols), LN=1: +LayerNorm+ReLU -> bf16 ===================
template<int LN>
__global__ __launch_bounds__(256)
void gemm_row256(const u16* __restrict__ A, const u16* __restrict__ WT,
                 const float* __restrict__ bias,
                 const float* __restrict__ g, const float* __restrict__ bvec,
                 u16* __restrict__ outb, float* __restrict__ outf)
{
    __shared__ u16 As[64 * 64];        // 8KB
    __shared__ u16 Bs[256 * 64];       // 32KB
    const int t = threadIdx.x, lane = t & 63, w = t >> 6;
    const size_t row0 = (size_t)blockIdx.x * 64;
    f32x4 acc[4][4] = {};
    for (int k0 = 0; k0 < 256; k0 += 64) {
        #pragma unroll
        for (int e = 0; e < 2; ++e) {
            const int u = t + (e << 8);
            const int r = u >> 3, kc = (u & 7) << 3;
            const int off = ((r << 7) + (kc << 1)) ^ ((r & 7) << 4);
            *(short8*)((char*)As + off) = *(const short8*)(A + (row0 + r) * 256 + k0 + kc);
        }
        #pragma unroll
        for (int e = 0; e < 8; ++e) {
            const int u = t + (e << 8);
            const int r = u >> 3, kc = (u & 7) << 3;
            const int off = ((r << 7) + (kc << 1)) ^ ((r & 7) << 4);
            *(short8*)((char*)Bs + off) = *(const short8*)(WT + (size_t)r * 256 + k0 + kc);
        }
        __syncthreads();
        #pragma unroll
        for (int kk = 0; kk < 64; kk += 32) {
            const int kbo = (kk + ((lane >> 4) << 3)) << 1;
            short8 af[4], bfr[4];
            #pragma unroll
            for (int i = 0; i < 4; ++i) {
                const int ra = (i << 4) + (lane & 15);
                af[i]  = *(const short8*)((const char*)As + (((ra << 7) + kbo) ^ ((ra & 7) << 4)));
                const int rb = (w << 6) + (i << 4) + (lane & 15);
                bfr[i] = *(const short8*)((const char*)Bs + (((rb << 7) + kbo) ^ ((rb & 7) << 4)));
            }
            #pragma unroll
            for (int mi = 0; mi < 4; ++mi)
                #pragma unroll
                for (int ni = 0; ni < 4; ++ni)
                    acc[mi][ni] = __builtin_amdgcn_mfma_f32_16x16x32_bf16(af[mi], bfr[ni], acc[mi][ni], 0, 0, 0);
        }
        __syncthreads();
    }
    const int cq = lane & 15, rq = (lane >> 4) << 2;
    #pragma unroll
    for (int ni = 0; ni < 4; ++ni) {
        const float bval = bias[(w << 6) + (ni << 4) + cq];
        #pragma unroll
        for (int mi = 0; mi < 4; ++mi)
            #pragma unroll
            for (int e = 0; e < 4; ++e)
                acc[mi][ni][e] += bval;
    }
    if (LN) {
        float* ws1 = (float*)As;            // [4 waves][64 rows]
        float* ws2 = ws1 + 256;
        float s1v[4][4], s2v[4][4];
        #pragma unroll
        for (int mi = 0; mi < 4; ++mi)
            #pragma unroll
            for (int e = 0; e < 4; ++e) {
                float s1 = 0.f, s2 = 0.f;
                #pragma unroll
                for (int ni = 0; ni < 4; ++ni) { const float y = acc[mi][ni][e]; s1 += y; s2 += y * y; }
                #pragma unroll
                for (int s = 8; s; s >>= 1) { s1 += __shfl_xor(s1, s, 64); s2 += __shfl_xor(s2, s, 64); }
                s1v[mi][e] = s1; s2v[mi][e] = s2;
            }
        if (cq == 0) {
            #pragma unroll
            for (int mi = 0; mi < 4; ++mi)
                #pragma unroll
                for (int e = 0; e < 4; ++e) {
                    const int r = (mi << 4) + rq + e;
                    ws1[(w << 6) + r] = s1v[mi][e];
                    ws2[(w << 6) + r] = s2v[mi][e];
                }
        }
        __syncthreads();
        float g4[4], b4[4];
        #pragma unroll
        for (int ni = 0; ni < 4; ++ni) {
            const int c = (w << 6) + (ni << 4) + cq;
            g4[ni] = g[c]; b4[ni] = bvec[c];
        }
        #pragma unroll
        for (int mi = 0; mi < 4; ++mi)
            #pragma unroll
            for (int e = 0; e < 4; ++e) {
                const int r = (mi << 4) + rq + e;
                const float s1 = ws1[r] + ws1[64 + r] + ws1[128 + r] + ws1[192 + r];
                const float s2 = ws2[r] + ws2[64 + r] + ws2[128 + r] + ws2[192 + r];
                const float mean = s1 * (1.0f / 256.0f);
                const float var = s2 * (1.0f / 256.0f) - mean * mean;
                const float rstd = 1.0f / sqrtf(var + 1e-5f);
                #pragma unroll
                for (int ni = 0; ni < 4; ++ni) {
                    const int c = (w << 6) + (ni << 4) + cq;
                    float y = (acc[mi][ni][e] - mean) * rstd * g4[ni] + b4[ni];
                    outb[(row0 + r) * 256 + c] = f2bf(fmaxf(y, 0.0f));
                }
            }
    } else {
        #pragma unroll
        for (int ni = 0; ni < 4; ++ni) {
            const int c = (w << 6) + (ni << 4) + cq;
            #pragma unroll
            for (int mi = 0; mi < 4; ++mi) {
                const size_t rbase = (row0 + (mi << 4) + rq) * 256 + c;
                #pragma unroll
                for (int e = 0; e < 4; ++e)
                    outf[rbase + (size_t)e * 256] = acc[mi][ni][e];
            }
        }
    }
}

extern "C" void kernel_launch(void* const* d_in, const int* in_sizes, int n_in,
                              void* d_out, int out_size, void* d_ws, size_t ws_size,
                              hipStream_t stream) {
    const float* src     = (const float*)d_in[0];
    const float* tgt     = (const float*)d_in[1];
    const float* src_fea = (const float*)d_in[2];
    const float* tgt_fea = (const float*)d_in[3];
    const float* Wq  = (const float*)d_in[4];   const float* bq  = (const float*)d_in[5];
    const float* Wk  = (const float*)d_in[6];   const float* bk  = (const float*)d_in[7];
    const float* Wv  = (const float*)d_in[8];   const float* bv  = (const float*)d_in[9];
    const float* Wo1 = (const float*)d_in[10];  const float* bo1 = (const float*)d_in[11];
    const float* lng = (const float*)d_in[12];  const float* lnb = (const float*)d_in[13];
    const float* Wo2 = (const float*)d_in[14];  const float* bo2 = (const float*)d_in[15];
    (void)in_sizes; (void)n_in; (void)out_size; (void)ws_size;

    float* out     = (float*)d_out;
    float* updated = out;                                   // [B,N,D] f32
    float* avg     = out + (size_t)BB * NN * DD;            // [B,N,M] f32

    char* p = (char*)d_ws;
    u16* WTq  = (u16*)p;   p += 256 * 256 * 2;
    u16* WTk  = (u16*)p;   p += 256 * 256 * 2;              // WTk|WTv contiguous = WTkv
    u16* WTv  = (u16*)p;   p += 256 * 256 * 2;
    u16* WTo1 = (u16*)p;   p += 256 * 256 * 2;
    u16* WTo2 = (u16*)p;   p += 256 * 256 * 2;
    float* Qb = (float*)p; p += (size_t)BB * NN * DD * 4;   // 4MB
    u16* Kbf  = (u16*)p;   p += (size_t)BB * MM * DD * 2;   // 4MB
    u16* Vbf  = (u16*)p;   p += (size_t)BB * MM * DD * 2;   // 4MB
    int* knn  = (int*)p;   p += (size_t)BB * NN * KNN * 4;  // 256KB
    u16* Xbf  = (u16*)p;   p += (size_t)BB * NN * DD * 2;   // 2MB
    u16* Hbf  = (u16*)p;   p += (size_t)BB * NN * DD * 2;   // 2MB

    dim3 blk(256);
    wtrans<<<80, blk, 0, stream>>>(Wq, Wk, Wv, Wo1, Wo2, WTq, WTk, WTv, WTo1, WTo2);
    mega_kernel<<<2816, blk, 0, stream>>>(src, tgt, knn, tgt_fea, src_fea, WTq, WTk,
                                          bq, bk, bv, Qb, Kbf, Vbf, avg);
    attn_kernel<<<BB * NN, blk, 0, stream>>>(Qb, Kbf, Vbf, knn, src_fea, Xbf, avg);
    gemm_row256<1><<<BB * NN / 64, blk, 0, stream>>>(Xbf, WTo1, bo1, lng, lnb, Hbf, nullptr);
    gemm_row256<0><<<BB * NN / 64, blk, 0, stream>>>(Hbf, WTo2, bo2, nullptr, nullptr, nullptr, updated);
}

// Round 6
// 183.706 us; speedup vs baseline: 1.4291x; 1.0968x over previous
//
#include <hip/hip_runtime.h>
#include <math.h>

#define BB 2
#define NN 2048
#define MM 4096
#define DD 256
#define HH 8
#define DK 32
#define KNN 16

typedef __attribute__((ext_vector_type(8))) short short8;
typedef __attribute__((ext_vector_type(4))) short short4v;
typedef __attribute__((ext_vector_type(4))) float f32x4;
typedef unsigned long long u64;
typedef unsigned short u16;

static __device__ __forceinline__ u16 f2bf(float f) {
    union { float f; unsigned u; } v; v.f = f;
    unsigned r = v.u + 0x7FFF + ((v.u >> 16) & 1);   // round-to-nearest-even
    return (u16)(r >> 16);
}
static __device__ __forceinline__ float bf2f(u16 u) {
    union { unsigned u; float f; } v; v.u = ((unsigned)u) << 16;
    return v.f;
}

// =================== wtrans: transpose + cvt the five 256x256 weights ===================
__global__ __launch_bounds__(256)
void wtrans(const float* W0, const float* W1, const float* W2, const float* W3, const float* W4,
            u16* O0, u16* O1, u16* O2, u16* O3, u16* O4)
{
    __shared__ float tile[64][65];
    const int bid = blockIdx.x;               // 5 * 16 blocks
    const int m = bid >> 4, tl = bid & 15;
    const int tr = (tl >> 2) * 64, tc = (tl & 3) * 64;
    const float* W = m == 0 ? W0 : m == 1 ? W1 : m == 2 ? W2 : m == 3 ? W3 : W4;
    u16*        O = m == 0 ? O0 : m == 1 ? O1 : m == 2 ? O2 : m == 3 ? O3 : O4;
    const int c = threadIdx.x & 63, r4 = threadIdx.x >> 6;
    #pragma unroll
    for (int i = 0; i < 16; ++i) {
        const int r = (r4 << 4) + i;
        tile[r][c] = W[(size_t)(tr + r) * 256 + tc + c];
    }
    __syncthreads();
    #pragma unroll
    for (int i = 0; i < 16; ++i) {
        const int cc = (r4 << 4) + i;
        O[(size_t)(tc + cc) * 256 + tr + c] = f2bf(tile[c][cc]);
    }
}

// 64x64-tile bf16 MFMA GEMM body; A staged from f32 with inline cvt.
static __device__ __forceinline__ void gemm64_body(
    const float* __restrict__ A, size_t row0, const u16* __restrict__ WT, int col0,
    u16* As, u16* Bs, int t, f32x4 acc[2][2])
{
    const int lane = t & 63, w = t >> 6;
    const int wr = (w >> 1) * 32, wc = (w & 1) * 32;
    for (int k0 = 0; k0 < 256; k0 += 64) {
        #pragma unroll
        for (int e = 0; e < 2; ++e) {
            const int flat = t + (e << 8);
            const int r = flat >> 3, kc = (flat & 7) << 3;
            const int off = ((r << 7) + (kc << 1)) ^ ((r & 7) << 4);
            const float* ap = A + (row0 + r) * 256 + k0 + kc;
            float4 a0 = *(const float4*)ap;
            float4 a1 = *(const float4*)(ap + 4);
            short8 s;
            s[0] = (short)f2bf(a0.x); s[1] = (short)f2bf(a0.y);
            s[2] = (short)f2bf(a0.z); s[3] = (short)f2bf(a0.w);
            s[4] = (short)f2bf(a1.x); s[5] = (short)f2bf(a1.y);
            s[6] = (short)f2bf(a1.z); s[7] = (short)f2bf(a1.w);
            *(short8*)((char*)As + off) = s;
            *(short8*)((char*)Bs + off) = *(const short8*)(WT + (size_t)(col0 + r) * 256 + k0 + kc);
        }
        __syncthreads();
        #pragma unroll
        for (int kk = 0; kk < 64; kk += 32) {
            const int kbo = (kk + ((lane >> 4) << 3)) << 1;
            short8 af[2], bfr[2];
            #pragma unroll
            for (int i = 0; i < 2; ++i) {
                const int ra = wr + (i << 4) + (lane & 15);
                af[i]  = *(const short8*)((const char*)As + (((ra << 7) + kbo) ^ ((ra & 7) << 4)));
                const int rb = wc + (i << 4) + (lane & 15);
                bfr[i] = *(const short8*)((const char*)Bs + (((rb << 7) + kbo) ^ ((rb & 7) << 4)));
            }
            #pragma unroll
            for (int mi = 0; mi < 2; ++mi)
                #pragma unroll
                for (int ni = 0; ni < 2; ++ni)
                    acc[mi][ni] = __builtin_amdgcn_mfma_f32_16x16x32_bf16(af[mi], bfr[ni], acc[mi][ni], 0, 0, 0);
        }
        __syncthreads();
    }
}

// =================== mega: knn + KV-GEMM + Q-GEMM + zero(avg), role-interleaved ===================
// 2816 blocks = 256 groups x 11 roles: 0-3 knn | 4-7 KV | 8 Q | 9-10 zero
__global__ __launch_bounds__(256, 4)
void mega_kernel(const float* __restrict__ src, const float* __restrict__ tgt,
                 int* __restrict__ knn_idx,
                 const float* __restrict__ tgt_fea, const float* __restrict__ src_fea,
                 const u16* __restrict__ WTq, const u16* __restrict__ WTkv,
                 const float* __restrict__ bq, const float* __restrict__ bk,
                 const float* __restrict__ bv,
                 float* __restrict__ Qb, u16* __restrict__ Kbf, u16* __restrict__ Vbf,
                 float* __restrict__ avg)
{
    __shared__ u16 As[64 * 64];   // 8KB
    __shared__ u16 Bs[64 * 64];   // 8KB
    const int bid = blockIdx.x;
    const int t = threadIdx.x;
    const int lane = t & 63;
    const int lid = bid / 11;
    const int role = bid % 11;

    if (role < 4) {
        // ---- kNN: wave-per-query; u32 fixed-point keys, top-20 superset, exact f64 re-rank.
        const int kb = lid * 4 + role;                 // 0..1023
        const int bn = (kb << 2) + (t >> 6);           // 0..4095
        const int b = bn >> 11;
        const float* sp = src + (size_t)bn * 3;
        const float px = sp[0], py = sp[1], pz = sp[2];
        const float x2 = px * px + py * py + pz * pz;
        const float* tb = tgt + (size_t)b * MM * 3;
        unsigned key[64];
        #pragma unroll
        for (int j = 0; j < 64; ++j) {
            const int m = (j << 6) + lane;
            const float tx = tb[m * 3 + 0], ty = tb[m * 3 + 1], tz = tb[m * 3 + 2];
            const float y2 = tx * tx + ty * ty + tz * tz;
            const float dt = px * tx + py * ty + pz * tz;
            float d = (x2 + y2) - 2.0f * dt;
            d = d > 0.f ? d : 0.f;
            const unsigned q20 = (unsigned)fminf(d * 32768.0f, 1048575.0f);
            key[j] = (q20 << 12) | (unsigned)m;
        }
        unsigned last1 = 0;
        unsigned mykey = 0xFFFFFFFFu;
        for (int sel = 0; sel < 20; ++sel) {
            unsigned c0 = ~0u, c1 = ~0u, c2 = ~0u, c3 = ~0u;
            #pragma unroll
            for (int j = 0; j < 64; j += 4) {
                const unsigned u0 = key[j + 0] - last1; c0 = u0 < c0 ? u0 : c0;
                const unsigned u1 = key[j + 1] - last1; c1 = u1 < c1 ? u1 : c1;
                const unsigned u2 = key[j + 2] - last1; c2 = u2 < c2 ? u2 : c2;
                const unsigned u3 = key[j + 3] - last1; c3 = u3 < c3 ? u3 : c3;
            }
            unsigned best = c0 < c1 ? c0 : c1;
            const unsigned bst2 = c2 < c3 ? c2 : c3;
            best = best < bst2 ? best : bst2;
            #pragma unroll
            for (int s = 32; s; s >>= 1) {
                const unsigned o = __shfl_xor(best, s, 64);
                best = o < best ? o : best;
            }
            const unsigned winner = best + last1;
            if (lane == sel) mykey = winner;
            last1 = winner + 1;
        }
        const int midx = (int)(mykey & 0xFFFu);
        u64 ex = ~0ULL;
        if (lane < 20) {                               // exact f64 distance, np-order key
            const float* tp = tb + (size_t)midx * 3;
            const double pxd = px, pyd = py, pzd = pz;
            const double tx = tp[0], ty = tp[1], tz = tp[2];
            const double x2d = pxd * pxd + pyd * pyd + pzd * pzd;
            const double y2d = tx * tx + ty * ty + tz * tz;
            const double dtd = pxd * tx + pyd * ty + pzd * tz;
            double dd = (x2d + y2d) - 2.0 * dtd;
            dd = dd > 0.0 ? dd : 0.0;
            ex = (((u64)__double_as_longlong(dd)) & ~0xFFFULL) | (u64)midx;
        }
        int rank = 0;
        #pragma unroll
        for (int i = 0; i < 20; ++i) {
            const u64 o = __shfl(ex, i, 64);
            rank += (o < ex) ? 1 : 0;
        }
        if (lane < 20 && rank < 16)
            knn_idx[(size_t)bn * KNN + rank] = midx;
        return;
    }

    if (role < 8) {
        // ---- KV GEMM: [8192][512] = tgt_fea @ [WTk|WTv]^T, bf16 out, 64x64 tile
        const int kvb = lid * 4 + (role - 4);          // 0..1023
        const size_t row0 = (size_t)(kvb >> 3) * 64;
        const int col0 = (kvb & 7) * 64;
        f32x4 acc[2][2] = {};
        gemm64_body(tgt_fea, row0, WTkv, col0, As, Bs, t, acc);
        const int w = t >> 6;
        const int wr = (w >> 1) * 32, wc = (w & 1) * 32;
        const bool isv = col0 >= 256;
        u16* ob = isv ? Vbf : Kbf;
        const float* bs = isv ? bv : bk;
        const int cb = (isv ? col0 - 256 : col0) + wc;
        const int cq = lane & 15, rq = (lane >> 4) << 2;
        #pragma unroll
        for (int ni = 0; ni < 2; ++ni) {
            const int c = cb + (ni << 4) + cq;
            const float bval = bs[c];
            #pragma unroll
            for (int mi = 0; mi < 2; ++mi) {
                const size_t r = row0 + wr + (mi << 4) + rq;
                #pragma unroll
                for (int e = 0; e < 4; ++e)
                    ob[(r + e) * 256 + c] = f2bf(acc[mi][ni][e] + bval);
            }
        }
        return;
    }

    if (role == 8) {
        // ---- Q GEMM: [4096][256] f32 = src_fea @ WTq^T, 64x64 tile
        const int qb = lid;                            // 0..255
        const size_t row0 = (size_t)(qb >> 2) * 64;
        const int col0 = (qb & 3) * 64;
        f32x4 acc[2][2] = {};
        gemm64_body(src_fea, row0, WTq, col0, As, Bs, t, acc);
        const int w = t >> 6;
        const int wr = (w >> 1) * 32, wc = (w & 1) * 32;
        const int cq = lane & 15, rq = (lane >> 4) << 2;
        #pragma unroll
        for (int ni = 0; ni < 2; ++ni) {
            const int c = col0 + wc + (ni << 4) + cq;
            const float bval = bq[c];
            #pragma unroll
            for (int mi = 0; mi < 2; ++mi) {
                const size_t rbase = (row0 + wr + (mi << 4) + rq) * 256 + c;
                #pragma unroll
                for (int e = 0; e < 4; ++e)
                    Qb[rbase + (size_t)e * 256] = acc[mi][ni][e] + bval;
            }
        }
        return;
    }

    // ---- zero avg_attn: 16.78M f32 via f32x4
    {
        const int zb = lid * 2 + (role - 9);           // 0..511
        f32x4 z = {0.f, 0.f, 0.f, 0.f};
        f32x4* pz = (f32x4*)avg;
        const int base = zb * 256 + t;
        #pragma unroll
        for (int i = 0; i < 32; ++i)
            pz[base + i * 131072] = z;
    }
}

// =================== attn v3: wave-per-query, register softmax ===================
// 1024 blocks x 4 waves; lane=(h,k2): h=lane>>3, k2=lane&7 (2 of 16 kNN per lane).
__global__ __launch_bounds__(256)
void attn_kernel(const float* __restrict__ Q, const u16* __restrict__ Kb,
                 const u16* __restrict__ Vb, const int* __restrict__ knn_idx,
                 const float* __restrict__ src_fea,
                 u16* __restrict__ Xb, float* __restrict__ avg_attn)
{
    __shared__ float q_sh[4][256];
    __shared__ float pw_sh[4][8][17];    // padded: 8 h-groups hit distinct banks
    __shared__ int   idx_sh[4][16];
    const int t = threadIdx.x;
    const int wid = t >> 6, lane = t & 63;
    const int bn = (blockIdx.x << 2) + wid;
    const int b = bn >> 11;
    const int h = lane >> 3, k2 = lane & 7;

    *(float4*)&q_sh[wid][lane << 2] = *(const float4*)(Q + (size_t)bn * 256 + (lane << 2));
    const int ia = knn_idx[(size_t)bn * KNN + k2];
    const int ib = knn_idx[(size_t)bn * KNN + 8 + k2];
    __syncthreads();

    // QK^T: two 32-dim dots per lane
    const u16* Ka = Kb + ((size_t)b * MM + ia) * 256 + h * DK;
    const u16* Kc = Kb + ((size_t)b * MM + ib) * 256 + h * DK;
    const float* qh = &q_sh[wid][h * DK];
    float s0 = 0.f, s1 = 0.f;
    #pragma unroll
    for (int j = 0; j < DK; j += 8) {
        const short8 ka = *(const short8*)(Ka + j);
        const short8 kc = *(const short8*)(Kc + j);
        #pragma unroll
        for (int e = 0; e < 8; ++e) {
            const float qv = qh[j + e];
            s0 = fmaf(qv, bf2f((u16)ka[e]), s0);
            s1 = fmaf(qv, bf2f((u16)kc[e]), s1);
        }
    }
    s0 *= 0.17677669529663688f;
    s1 *= 0.17677669529663688f;

    // softmax over 16 scores within the 8-lane h-group (lane bits 0-2)
    float m = fmaxf(s0, s1);
    m = fmaxf(m, __shfl_xor(m, 1, 64));
    m = fmaxf(m, __shfl_xor(m, 2, 64));
    m = fmaxf(m, __shfl_xor(m, 4, 64));
    const float e0 = expf(s0 - m), e1 = expf(s1 - m);
    float sum = e0 + e1;
    sum += __shfl_xor(sum, 1, 64);
    sum += __shfl_xor(sum, 2, 64);
    sum += __shfl_xor(sum, 4, 64);
    const float inv = 1.0f / sum;
    const float p0 = e0 * inv, p1 = e1 * inv;

    // head-average (lane bits 3-5) -> scatter avg_attn
    float a0 = p0, a1 = p1;
    a0 += __shfl_xor(a0, 8, 64);  a1 += __shfl_xor(a1, 8, 64);
    a0 += __shfl_xor(a0, 16, 64); a1 += __shfl_xor(a1, 16, 64);
    a0 += __shfl_xor(a0, 32, 64); a1 += __shfl_xor(a1, 32, 64);
    if (h == 0) {
        avg_attn[(size_t)bn * MM + ia] = a0 * 0.125f;
        avg_attn[(size_t)bn * MM + ib] = a1 * 0.125f;
        idx_sh[wid][k2] = ia;
        idx_sh[wid][8 + k2] = ib;
    }
    pw_sh[wid][h][k2] = p0;
    pw_sh[wid][h][8 + k2] = p1;
    __syncthreads();

    // PV: lane owns 4 output dims (d0..d0+3), all in head h2 = lane>>3
    const int d0 = lane << 2;
    const int h2 = lane >> 3;
    float o0 = 0.f, o1 = 0.f, o2 = 0.f, o3 = 0.f;
    #pragma unroll
    for (int k = 0; k < KNN; ++k) {
        const float p = pw_sh[wid][h2][k];
        const int ik = idx_sh[wid][k];
        const short4v v4 = *(const short4v*)(Vb + ((size_t)b * MM + ik) * 256 + d0);
        o0 = fmaf(p, bf2f((u16)v4[0]), o0);
        o1 = fmaf(p, bf2f((u16)v4[1]), o1);
        o2 = fmaf(p, bf2f((u16)v4[2]), o2);
        o3 = fmaf(p, bf2f((u16)v4[3]), o3);
    }
    const float4 sf = *(const float4*)(src_fea + (size_t)bn * 256 + d0);
    short4v xo;
    xo[0] = (short)f2bf(o0 + sf.x);
    xo[1] = (short)f2bf(o1 + sf.y);
    xo[2] = (short)f2bf(o2 + sf.z);
    xo[3] = (short)f2bf(o3 + sf.w);
    *(short4v*)(Xb + (size_t)bn * 256 + d0) = xo;
}

// =================== Wo1 GEMM (32 rows x 256 cols) + LayerNorm + ReLU -> bf16 ===================
__global__ __launch_bounds__(256)
void gemm_wo1_ln(const u16* __restrict__ A, const u16* __restrict__ WT,
                 const float* __restrict__ bias,
                 const float* __restrict__ g, const float* __restrict__ bvec,
                 u16* __restrict__ outb)
{
    __shared__ u16 As[32 * 64];        // 4KB
    __shared__ u16 Bs[256 * 64];       // 32KB
    const int t = threadIdx.x, lane = t & 63, w = t >> 6;
    const size_t row0 = (size_t)blockIdx.x * 32;
    f32x4 acc[2][4] = {};
    for (int k0 = 0; k0 < 256; k0 += 64) {
        {
            const int r = t >> 3, kc = (t & 7) << 3;
            const int off = ((r << 7) + (kc << 1)) ^ ((r & 7) << 4);
            *(short8*)((char*)As + off) = *(const short8*)(A + (row0 + r) * 256 + k0 + kc);
        }
        #pragma unroll
        for (int e = 0; e < 8; ++e) {
            const int u = t + (e << 8);
            const int r = u >> 3, kc = (u & 7) << 3;
            const int off = ((r << 7) + (kc << 1)) ^ ((r & 7) << 4);
            *(short8*)((char*)Bs + off) = *(const short8*)(WT + (size_t)r * 256 + k0 + kc);
        }
        __syncthreads();
        #pragma unroll
        for (int kk = 0; kk < 64; kk += 32) {
            const int kbo = (kk + ((lane >> 4) << 3)) << 1;
            short8 af[2], bfr[4];
            #pragma unroll
            for (int i = 0; i < 2; ++i) {
                const int ra = (i << 4) + (lane & 15);
                af[i] = *(const short8*)((const char*)As + (((ra << 7) + kbo) ^ ((ra & 7) << 4)));
            }
            #pragma unroll
            for (int i = 0; i < 4; ++i) {
                const int rb = (w << 6) + (i << 4) + (lane & 15);
                bfr[i] = *(const short8*)((const char*)Bs + (((rb << 7) + kbo) ^ ((rb & 7) << 4)));
            }
            #pragma unroll
            for (int mi = 0; mi < 2; ++mi)
                #pragma unroll
                for (int ni = 0; ni < 4; ++ni)
                    acc[mi][ni] = __builtin_amdgcn_mfma_f32_16x16x32_bf16(af[mi], bfr[ni], acc[mi][ni], 0, 0, 0);
        }
        __syncthreads();
    }
    const int cq = lane & 15, rq = (lane >> 4) << 2;
    #pragma unroll
    for (int ni = 0; ni < 4; ++ni) {
        const float bval = bias[(w << 6) + (ni << 4) + cq];
        #pragma unroll
        for (int mi = 0; mi < 2; ++mi)
            #pragma unroll
            for (int e = 0; e < 4; ++e)
                acc[mi][ni][e] += bval;
    }
    // LayerNorm across the 256 cols (4 waves x 64 cols each)
    float* ws1 = (float*)As;             // [4][32]
    float* ws2 = ws1 + 128;
    #pragma unroll
    for (int mi = 0; mi < 2; ++mi)
        #pragma unroll
        for (int e = 0; e < 4; ++e) {
            float s1 = 0.f, s2 = 0.f;
            #pragma unroll
            for (int ni = 0; ni < 4; ++ni) { const float y = acc[mi][ni][e]; s1 += y; s2 += y * y; }
            s1 += __shfl_xor(s1, 1, 64); s2 += __shfl_xor(s2, 1, 64);
            s1 += __shfl_xor(s1, 2, 64); s2 += __shfl_xor(s2, 2, 64);
            s1 += __shfl_xor(s1, 4, 64); s2 += __shfl_xor(s2, 4, 64);
            s1 += __shfl_xor(s1, 8, 64); s2 += __shfl_xor(s2, 8, 64);
            if (cq == 0) {
                const int r = (mi << 4) + rq + e;
                ws1[(w << 5) + r] = s1;
                ws2[(w << 5) + r] = s2;
            }
        }
    __syncthreads();
    float g4[4], b4[4];
    #pragma unroll
    for (int ni = 0; ni < 4; ++ni) {
        const int c = (w << 6) + (ni << 4) + cq;
        g4[ni] = g[c]; b4[ni] = bvec[c];
    }
    #pragma unroll
    for (int mi = 0; mi < 2; ++mi)
        #pragma unroll
        for (int e = 0; e < 4; ++e) {
            const int r = (mi << 4) + rq + e;
            const float s1 = ws1[r] + ws1[32 + r] + ws1[64 + r] + ws1[96 + r];
            const float s2 = ws2[r] + ws2[32 + r] + ws2[64 + r] + ws2[96 + r];
            const float mean = s1 * (1.0f / 256.0f);
            const float var = s2 * (1.0f / 256.0f) - mean * mean;
            const float rstd = 1.0f / sqrtf(var + 1e-5f);
            #pragma unroll
            for (int ni = 0; ni < 4; ++ni) {
                const int c = (w << 6) + (ni << 4) + cq;
                const float y = (acc[mi][ni][e] - mean) * rstd * g4[ni] + b4[ni];
                outb[(row0 + r) * 256 + c] = f2bf(fmaxf(y, 0.0f));
            }
        }
}

// =================== Wo2 GEMM (32 rows x 128 cols) -> f32 ===================
__global__ __launch_bounds__(256)
void gemm_wo2(const u16* __restrict__ A, const u16* __restrict__ WT,
              const float* __restrict__ bias, float* __restrict__ outf)
{
    __shared__ u16 As[32 * 64];        // 4KB
    __shared__ u16 Bs[128 * 64];       // 16KB
    const int t = threadIdx.x, lane = t & 63, w = t >> 6;
    const size_t row0 = (size_t)(blockIdx.x >> 1) * 32;
    const int col0 = (blockIdx.x & 1) * 128;
    f32x4 acc[2][2] = {};
    for (int k0 = 0; k0 < 256; k0 += 64) {
        {
            const int r = t >> 3, kc = (t & 7) << 3;
            const int off = ((r << 7) + (kc << 1)) ^ ((r & 7) << 4);
            *(short8*)((char*)As + off) = *(const short8*)(A + (row0 + r) * 256 + k0 + kc);
        }
        #pragma unroll
        for (int e = 0; e < 4; ++e) {
            const int u = t + (e << 8);
            const int r = u >> 3, kc = (u & 7) << 3;
            const int off = ((r << 7) + (kc << 1)) ^ ((r & 7) << 4);
            *(short8*)((char*)Bs + off) = *(const short8*)(WT + (size_t)(col0 + r) * 256 + k0 + kc);
        }
        __syncthreads();
        #pragma unroll
        for (int kk = 0; kk < 64; kk += 32) {
            const int kbo = (kk + ((lane >> 4) << 3)) << 1;
            short8 af[2], bfr[2];
            #pragma unroll
            for (int i = 0; i < 2; ++i) {
                const int ra = (i << 4) + (lane & 15);
                af[i] = *(const short8*)((const char*)As + (((ra << 7) + kbo) ^ ((ra & 7) << 4)));
                const int rb = (w << 5) + (i << 4) + (lane & 15);
                bfr[i] = *(const short8*)((const char*)Bs + (((rb << 7) + kbo) ^ ((rb & 7) << 4)));
            }
            #pragma unroll
            for (int mi = 0; mi < 2; ++mi)
                #pragma unroll
                for (int ni = 0; ni < 2; ++ni)
                    acc[mi][ni] = __builtin_amdgcn_mfma_f32_16x16x32_bf16(af[mi], bfr[ni], acc[mi][ni], 0, 0, 0);
        }
        __syncthreads();
    }
    const int cq = lane & 15, rq = (lane >> 4) << 2;
    #pragma unroll
    for (int ni = 0; ni < 2; ++ni) {
        const int c = col0 + (w << 5) + (ni << 4) + cq;
        const float bval = bias[c];
        #pragma unroll
        for (int mi = 0; mi < 2; ++mi) {
            const size_t rbase = (row0 + (mi << 4) + rq) * 256 + c;
            #pragma unroll
            for (int e = 0; e < 4; ++e)
                outf[rbase + (size_t)e * 256] = acc[mi][ni][e] + bval;
        }
    }
}

extern "C" void kernel_launch(void* const* d_in, const int* in_sizes, int n_in,
                              void* d_out, int out_size, void* d_ws, size_t ws_size,
                              hipStream_t stream) {
    const float* src     = (const float*)d_in[0];
    const float* tgt     = (const float*)d_in[1];
    const float* src_fea = (const float*)d_in[2];
    const float* tgt_fea = (const float*)d_in[3];
    const float* Wq  = (const float*)d_in[4];   const float* bq  = (const float*)d_in[5];
    const float* Wk  = (const float*)d_in[6];   const float* bk  = (const float*)d_in[7];
    const float* Wv  = (const float*)d_in[8];   const float* bv  = (const float*)d_in[9];
    const float* Wo1 = (const float*)d_in[10];  const float* bo1 = (const float*)d_in[11];
    const float* lng = (const float*)d_in[12];  const float* lnb = (const float*)d_in[13];
    const float* Wo2 = (const float*)d_in[14];  const float* bo2 = (const float*)d_in[15];
    (void)in_sizes; (void)n_in; (void)out_size; (void)ws_size;

    float* out     = (float*)d_out;
    float* updated = out;                                   // [B,N,D] f32
    float* avg     = out + (size_t)BB * NN * DD;            // [B,N,M] f32

    char* p = (char*)d_ws;
    u16* WTq  = (u16*)p;   p += 256 * 256 * 2;
    u16* WTk  = (u16*)p;   p += 256 * 256 * 2;              // WTk|WTv contiguous = WTkv
    u16* WTv  = (u16*)p;   p += 256 * 256 * 2;
    u16* WTo1 = (u16*)p;   p += 256 * 256 * 2;
    u16* WTo2 = (u16*)p;   p += 256 * 256 * 2;
    float* Qb = (float*)p; p += (size_t)BB * NN * DD * 4;   // 4MB
    u16* Kbf  = (u16*)p;   p += (size_t)BB * MM * DD * 2;   // 4MB
    u16* Vbf  = (u16*)p;   p += (size_t)BB * MM * DD * 2;   // 4MB
    int* knn  = (int*)p;   p += (size_t)BB * NN * KNN * 4;  // 256KB
    u16* Xbf  = (u16*)p;   p += (size_t)BB * NN * DD * 2;   // 2MB
    u16* Hbf  = (u16*)p;   p += (size_t)BB * NN * DD * 2;   // 2MB

    dim3 blk(256);
    wtrans<<<80, blk, 0, stream>>>(Wq, Wk, Wv, Wo1, Wo2, WTq, WTk, WTv, WTo1, WTo2);
    mega_kernel<<<2816, blk, 0, stream>>>(src, tgt, knn, tgt_fea, src_fea, WTq, WTk,
                                          bq, bk, bv, Qb, Kbf, Vbf, avg);
    attn_kernel<<<BB * NN / 4, blk, 0, stream>>>(Qb, Kbf, Vbf, knn, src_fea, Xbf, avg);
    gemm_wo1_ln<<<BB * NN / 32, blk, 0, stream>>>(Xbf, WTo1, bo1, lng, lnb, Hbf);
    gemm_wo2<<<BB * NN / 16, blk, 0, stream>>>(Hbf, WTo2, bo2, updated);
}